// Round 4
// baseline (1699.897 us; speedup 1.0000x reference)
//
#include <hip/hip_runtime.h>
#include <hip/hip_bf16.h>

#define NN 50000
#define NE 1000000
#define DIM 64
#define NG 256
#define NBUCK 196      // ceil(NN/256) buckets of 256 dst nodes
#define BCAP 6144      // global capacity per bucket (avg 5102, +14 sigma)
#define ROUND 4096     // edges per block in bucket_fill
#define SCAP 48        // LDS stage slots per bucket (avg fill ~21)

// ---- single-pass coarse bucketing with LDS-staged coalesced flushes ----
// bucketData[b*BCAP + i] = (dst & 255) << 16 | src   (src < 2^16)
__global__ __launch_bounds__(512) void bucket_fill_kernel(
    const int* __restrict__ src, const int* __restrict__ dst,
    unsigned int* __restrict__ bucketData, int* __restrict__ gcursor) {
    __shared__ unsigned int stage[NBUCK * SCAP];   // 37.6 KB
    __shared__ int cnt[NBUCK];
    int t = threadIdx.x;
    for (int i = t; i < NBUCK; i += 512) cnt[i] = 0;
    __syncthreads();
    int base = blockIdx.x * ROUND;
#pragma unroll
    for (int it = 0; it < 8; ++it) {
        int e = base + it * 512 + t;          // coalesced across the wave
        if (e < NE) {
            int d = dst[e];
            int s = src[e];
            int b = d >> 8;
            unsigned int val = ((unsigned int)(d & 255) << 16) | (unsigned int)s;
            int slot = atomicAdd(&cnt[b], 1);
            if (slot < SCAP) {
                stage[b * SCAP + slot] = val;
            } else {                           // rare overflow: direct append
                int pos = atomicAdd(&gcursor[b], 1);
                if (pos < BCAP) bucketData[(size_t)b * BCAP + pos] = val;
            }
        }
    }
    __syncthreads();
    int w = t >> 6, lane = t & 63;
    for (int b = w; b < NBUCK; b += 8) {       // one wave flushes a bucket
        int n = cnt[b]; if (n > SCAP) n = SCAP;
        if (n == 0) continue;
        int gbase = 0;
        if (lane == 0) gbase = atomicAdd(&gcursor[b], n);
        gbase = __shfl(gbase, 0, 64);
        if (lane < n) {                        // n <= 48: one coalesced run
            int pos = gbase + lane;
            if (pos < BCAP) bucketData[(size_t)b * BCAP + pos] = stage[b * SCAP + lane];
        }
    }
}

// ---------- H = X @ W : thread-per-row, W via wave-uniform (scalar) loads ----------
__global__ __launch_bounds__(128) void gemm64_kernel(const float* __restrict__ X,
                                                     const float* __restrict__ W,
                                                     float* __restrict__ H, int nrows) {
    __shared__ float Xl[128 * 65];
    int t = threadIdx.x;
    int base = blockIdx.x * 128;
    for (int idx = t; idx < 128 * 16; idx += 128) {
        int row = idx >> 4;
        int c4  = idx & 15;
        float4 v = make_float4(0.f, 0.f, 0.f, 0.f);
        if (base + row < nrows)
            v = *reinterpret_cast<const float4*>(&X[(size_t)(base + row) * 64 + c4 * 4]);
        float* p = &Xl[row * 65 + c4 * 4];
        p[0] = v.x; p[1] = v.y; p[2] = v.z; p[3] = v.w;
    }
    __syncthreads();
    float acc[64];
#pragma unroll
    for (int c = 0; c < 64; ++c) acc[c] = 0.f;
#pragma unroll 4
    for (int k = 0; k < 64; ++k) {
        float xv = Xl[t * 65 + k];
#pragma unroll
        for (int c4 = 0; c4 < 16; ++c4) {
            float4 w = *reinterpret_cast<const float4*>(&W[k * 64 + c4 * 4]);
            acc[c4 * 4 + 0] = fmaf(xv, w.x, acc[c4 * 4 + 0]);
            acc[c4 * 4 + 1] = fmaf(xv, w.y, acc[c4 * 4 + 1]);
            acc[c4 * 4 + 2] = fmaf(xv, w.z, acc[c4 * 4 + 2]);
            acc[c4 * 4 + 3] = fmaf(xv, w.w, acc[c4 * 4 + 3]);
        }
    }
    int row = base + t;
    if (row < nrows) {
#pragma unroll
        for (int c4 = 0; c4 < 16; ++c4) {
            float4 o = make_float4(acc[c4 * 4 + 0], acc[c4 * 4 + 1],
                                   acc[c4 * 4 + 2], acc[c4 * 4 + 3]);
            *reinterpret_cast<float4*>(&H[(size_t)row * 64 + c4 * 4]) = o;
        }
    }
}

// ---- per-bucket LDS-accumulated aggregation + ReLU + Xout + fused pool ----
__global__ __launch_bounds__(1024) void gather_kernel(
    const float* __restrict__ H, const unsigned int* __restrict__ bucketData,
    const int* __restrict__ gcursor, const int* __restrict__ batch,
    float* __restrict__ Xout, float* __restrict__ pool) {
    __shared__ float acc[256 * DIM];   // 64 KB
    int t = threadIdx.x;
    for (int i = t; i < 256 * DIM; i += 1024) acc[i] = 0.f;
    __syncthreads();
    int b = blockIdx.x;
    int count = gcursor[b]; if (count > BCAP) count = BCAP;
    const unsigned int* bd = bucketData + (size_t)b * BCAP;
    int w = t >> 6, lane = t & 63;
    int chunk = (count + 15) >> 4;     // 16 waves share the bucket
    int beg = w * chunk;
    int end = min(beg + chunk, count);
    int e = beg;
    for (; e + 4 <= end; e += 4) {     // 4-deep ILP over chained latencies
        unsigned int v0 = bd[e], v1 = bd[e + 1], v2 = bd[e + 2], v3 = bd[e + 3];
        float h0 = H[(size_t)(v0 & 0xFFFFu) * DIM + lane];
        float h1 = H[(size_t)(v1 & 0xFFFFu) * DIM + lane];
        float h2 = H[(size_t)(v2 & 0xFFFFu) * DIM + lane];
        float h3 = H[(size_t)(v3 & 0xFFFFu) * DIM + lane];
        atomicAdd(&acc[(v0 >> 16) * DIM + lane], h0);   // ds_add_f32, bank-clean
        atomicAdd(&acc[(v1 >> 16) * DIM + lane], h1);
        atomicAdd(&acc[(v2 >> 16) * DIM + lane], h2);
        atomicAdd(&acc[(v3 >> 16) * DIM + lane], h3);
    }
    for (; e < end; ++e) {
        unsigned int v = bd[e];
        float hv = H[(size_t)(v & 0xFFFFu) * DIM + lane];
        atomicAdd(&acc[(v >> 16) * DIM + lane], hv);
    }
    __syncthreads();
    // wave w owns nodes [w*16, w*16+16): relu, write, pool (batch sorted)
    int nodebase = b * 256 + w * 16;
    float run = 0.f;
    int curg = -1;
    for (int i = 0; i < 16; ++i) {
        int node = nodebase + i;
        if (node >= NN) break;                       // wave-uniform
        float v = fmaxf(acc[(w * 16 + i) * DIM + lane], 0.f);
        Xout[(size_t)node * DIM + lane] = v;
        int g = batch[node];
        if (g != curg) {                             // wave-uniform
            if (curg >= 0) unsafeAtomicAdd(&pool[(size_t)curg * DIM + lane], run);
            run = 0.f; curg = g;
        }
        run += v;
    }
    if (curg >= 0) unsafeAtomicAdd(&pool[(size_t)curg * DIM + lane], run);
}

// ---------- out[g] = relu(sum_l pool_l[g] @ Wp_l) ----------
__global__ void final_kernel(const float* __restrict__ P1, const float* __restrict__ P2,
                             const float* __restrict__ P3,
                             const float* __restrict__ Wp1, const float* __restrict__ Wp2,
                             const float* __restrict__ Wp3, float* __restrict__ out) {
    int g = blockIdx.x;
    int c = threadIdx.x;  // 64
    float acc = 0.f;
#pragma unroll
    for (int k = 0; k < 64; ++k) {
        acc = fmaf(P1[g * 64 + k], Wp1[k * 64 + c], acc);
        acc = fmaf(P2[g * 64 + k], Wp2[k * 64 + c], acc);
        acc = fmaf(P3[g * 64 + k], Wp3[k * 64 + c], acc);
    }
    out[g * 64 + c] = fmaxf(acc, 0.f);
}

extern "C" void kernel_launch(void* const* d_in, const int* in_sizes, int n_in,
                              void* d_out, int out_size, void* d_ws, size_t ws_size,
                              hipStream_t stream) {
    const float* x     = (const float*)d_in[0];
    const int*   eidx  = (const int*)d_in[1];   // [2, NE]
    const int*   batch = (const int*)d_in[2];   // [NN], sorted
    const float* W1  = (const float*)d_in[3];
    const float* W2  = (const float*)d_in[4];
    const float* W3  = (const float*)d_in[5];
    const float* Wp1 = (const float*)d_in[6];
    const float* Wp2 = (const float*)d_in[7];
    const float* Wp3 = (const float*)d_in[8];
    float* out = (float*)d_out;

    const int* src = eidx;
    const int* dst = eidx + NE;

    // ---- workspace layout (~30.6 MB) ----
    float* bufA  = (float*)d_ws;                        // H    (12.8 MB)
    float* bufB  = bufA + (size_t)NN * DIM;             // x_l  (12.8 MB)
    float* pool1 = bufB + (size_t)NN * DIM;             // 3 x 64 KB
    float* pool2 = pool1 + (size_t)NG * DIM;
    float* pool3 = pool2 + (size_t)NG * DIM;
    unsigned int* bucketData = (unsigned int*)(pool3 + (size_t)NG * DIM); // 4.8 MB
    int* gcursor = (int*)(bucketData + (size_t)NBUCK * BCAP);            // 784 B

    hipMemsetAsync(pool1, 0, (size_t)3 * NG * DIM * sizeof(float), stream);
    hipMemsetAsync(gcursor, 0, (size_t)NBUCK * sizeof(int), stream);

    // ---- bucket edges once; reused by all 3 layers ----
    const int fill_blocks = (NE + ROUND - 1) / ROUND;   // 245
    bucket_fill_kernel<<<fill_blocks, 512, 0, stream>>>(src, dst, bucketData, gcursor);

    const int gemm_blocks = (NN + 127) / 128;           // 391

    const float* xin = x;
    const float* Ws[3]   = {W1, W2, W3};
    float* pools[3] = {pool1, pool2, pool3};
    for (int l = 0; l < 3; ++l) {
        gemm64_kernel<<<gemm_blocks, 128, 0, stream>>>(xin, Ws[l], bufA, NN);
        gather_kernel<<<NBUCK, 1024, 0, stream>>>(bufA, bucketData, gcursor, batch, bufB, pools[l]);
        xin = bufB;
    }
    final_kernel<<<NG, 64, 0, stream>>>(pool1, pool2, pool3, Wp1, Wp2, Wp3, out);
}

// Round 6
// 547.117 us; speedup vs baseline: 3.1070x; 3.1070x over previous
//
#include <hip/hip_runtime.h>
#include <hip/hip_bf16.h>

#define NN 50000
#define NE 1000000
#define DIM 64
#define NG 256
#define NBUCK 196      // ceil(NN/256) buckets of 256 dst nodes
#define BCAP 6144      // per-bucket capacity (avg 5102, +14 sigma)
#define ROUND 4096     // edges per block in bucket_fill
#define SCAP 48        // LDS stage slots per bucket

// ---- pass 1: coarse bucketing with LDS-staged coalesced flushes ----
// bucketData[b*BCAP + i] = (dst & 255) << 16 | src   (src < 2^16)
__global__ __launch_bounds__(512) void bucket_fill_kernel(
    const int* __restrict__ src, const int* __restrict__ dst,
    unsigned int* __restrict__ bucketData, int* __restrict__ gcursor) {
    __shared__ unsigned int stage[NBUCK * SCAP];   // 37.6 KB
    __shared__ int cnt[NBUCK];
    int t = threadIdx.x;
    for (int i = t; i < NBUCK; i += 512) cnt[i] = 0;
    __syncthreads();
    int base = blockIdx.x * ROUND;
#pragma unroll
    for (int it = 0; it < 8; ++it) {
        int e = base + it * 512 + t;
        if (e < NE) {
            int d = dst[e];
            int s = src[e];
            int b = d >> 8;
            unsigned int val = ((unsigned int)(d & 255) << 16) | (unsigned int)s;
            int slot = atomicAdd(&cnt[b], 1);
            if (slot < SCAP) {
                stage[b * SCAP + slot] = val;
            } else {                           // rare overflow: direct append
                int pos = atomicAdd(&gcursor[b], 1);
                if (pos < BCAP) bucketData[(size_t)b * BCAP + pos] = val;
            }
        }
    }
    __syncthreads();
    int w = t >> 6, lane = t & 63;
    for (int b = w; b < NBUCK; b += 8) {
        int n = cnt[b]; if (n > SCAP) n = SCAP;
        if (n == 0) continue;
        int gbase = 0;
        if (lane == 0) gbase = atomicAdd(&gcursor[b], n);
        gbase = __shfl(gbase, 0, 64);
        if (lane < n) {
            int pos = gbase + lane;
            if (pos < BCAP) bucketData[(size_t)b * BCAP + pos] = stage[b * SCAP + lane];
        }
    }
}

// ---- pass 2a: exclusive scan of bucket counts (1 block) ----
__global__ void bucket_base_kernel(const int* __restrict__ gcursor,
                                   int* __restrict__ bucketBase,
                                   int* __restrict__ offsets) {
    __shared__ int sc[256];
    int t = threadIdx.x;
    int v = (t < NBUCK) ? min(gcursor[t], BCAP) : 0;
    sc[t] = v;
    __syncthreads();
    for (int off = 1; off < 256; off <<= 1) {
        int a = (t >= off) ? sc[t - off] : 0;
        __syncthreads();
        sc[t] += a;
        __syncthreads();
    }
    if (t < NBUCK) bucketBase[t] = sc[t] - v;     // exclusive
    if (t == NBUCK - 1) { bucketBase[NBUCK] = sc[t]; offsets[NN] = sc[t]; }
}

// ---- pass 2b: per-bucket counting sort -> exact CSR (localized writes) ----
__global__ __launch_bounds__(512) void bucket_sort_kernel(
    const unsigned int* __restrict__ bucketData, const int* __restrict__ gcursor,
    const int* __restrict__ bucketBase, int* __restrict__ offsets,
    int* __restrict__ csr) {
    __shared__ int hist[256];
    __shared__ int sc[256];
    __shared__ int cur[256];
    int b = blockIdx.x;
    int t = threadIdx.x;
    if (t < 256) hist[t] = 0;
    __syncthreads();
    int count = min(gcursor[b], BCAP);
    const unsigned int* bd = bucketData + (size_t)b * BCAP;
    for (int e = t; e < count; e += 512) atomicAdd(&hist[bd[e] >> 16], 1);
    __syncthreads();
    if (t < 256) sc[t] = hist[t];
    __syncthreads();
    for (int off = 1; off < 256; off <<= 1) {
        int a = 0;
        if (t < 256 && t >= off) a = sc[t - off];
        __syncthreads();
        if (t < 256) sc[t] += a;
        __syncthreads();
    }
    int gbase = bucketBase[b];
    if (t < 256) {
        int excl = sc[t] - hist[t];
        cur[t] = excl;
        int node = b * 256 + t;
        if (node < NN) offsets[node] = gbase + excl;
    }
    __syncthreads();
    for (int e = t; e < count; e += 512) {
        unsigned int v = bd[e];
        int p = atomicAdd(&cur[v >> 16], 1);
        csr[gbase + p] = (int)(v & 0xFFFFu);      // writes land in ~20KB range
    }
}

// ---------- H = X @ W : thread-per-row, W via wave-uniform (scalar) loads ----------
__global__ __launch_bounds__(128) void gemm64_kernel(const float* __restrict__ X,
                                                     const float* __restrict__ W,
                                                     float* __restrict__ H, int nrows) {
    __shared__ float Xl[128 * 65];
    int t = threadIdx.x;
    int base = blockIdx.x * 128;
    for (int idx = t; idx < 128 * 16; idx += 128) {
        int row = idx >> 4;
        int c4  = idx & 15;
        float4 v = make_float4(0.f, 0.f, 0.f, 0.f);
        if (base + row < nrows)
            v = *reinterpret_cast<const float4*>(&X[(size_t)(base + row) * 64 + c4 * 4]);
        float* p = &Xl[row * 65 + c4 * 4];
        p[0] = v.x; p[1] = v.y; p[2] = v.z; p[3] = v.w;
    }
    __syncthreads();
    float acc[64];
#pragma unroll
    for (int c = 0; c < 64; ++c) acc[c] = 0.f;
#pragma unroll 4
    for (int k = 0; k < 64; ++k) {
        float xv = Xl[t * 65 + k];
#pragma unroll
        for (int c4 = 0; c4 < 16; ++c4) {
            float4 w = *reinterpret_cast<const float4*>(&W[k * 64 + c4 * 4]);
            acc[c4 * 4 + 0] = fmaf(xv, w.x, acc[c4 * 4 + 0]);
            acc[c4 * 4 + 1] = fmaf(xv, w.y, acc[c4 * 4 + 1]);
            acc[c4 * 4 + 2] = fmaf(xv, w.z, acc[c4 * 4 + 2]);
            acc[c4 * 4 + 3] = fmaf(xv, w.w, acc[c4 * 4 + 3]);
        }
    }
    int row = base + t;
    if (row < nrows) {
#pragma unroll
        for (int c4 = 0; c4 < 16; ++c4) {
            float4 o = make_float4(acc[c4 * 4 + 0], acc[c4 * 4 + 1],
                                   acc[c4 * 4 + 2], acc[c4 * 4 + 3]);
            *reinterpret_cast<float4*>(&H[(size_t)row * 64 + c4 * 4]) = o;
        }
    }
}

// ---------- per-node CSR gather + ReLU + fused add-pool (R3-proven) ----------
__global__ void gather_kernel(const float* __restrict__ H, const int* __restrict__ offsets,
                              const int* __restrict__ csr, const int* __restrict__ batch,
                              float* __restrict__ Xout, float* __restrict__ pool) {
    int tid = blockIdx.x * blockDim.x + threadIdx.x;
    int lane = tid & 63;
    int gw = tid >> 6;
    int nw = (gridDim.x * blockDim.x) >> 6;
    for (int n = gw; n < NN; n += nw) {
        int beg = offsets[n], end = offsets[n + 1];
        float a0 = 0.f, a1 = 0.f, a2 = 0.f, a3 = 0.f;
        int i = beg;
        for (; i + 4 <= end; i += 4) {
            int s0 = csr[i], s1 = csr[i + 1], s2 = csr[i + 2], s3 = csr[i + 3];
            a0 += H[(size_t)s0 * 64 + lane];
            a1 += H[(size_t)s1 * 64 + lane];
            a2 += H[(size_t)s2 * 64 + lane];
            a3 += H[(size_t)s3 * 64 + lane];
        }
        for (; i < end; ++i) a0 += H[(size_t)csr[i] * 64 + lane];
        float v = fmaxf((a0 + a1) + (a2 + a3), 0.f);
        Xout[(size_t)n * 64 + lane] = v;
        unsafeAtomicAdd(&pool[(size_t)batch[n] * 64 + lane], v);
    }
}

// ---------- out[g] = relu(sum_l pool_l[g] @ Wp_l) ----------
__global__ void final_kernel(const float* __restrict__ P1, const float* __restrict__ P2,
                             const float* __restrict__ P3,
                             const float* __restrict__ Wp1, const float* __restrict__ Wp2,
                             const float* __restrict__ Wp3, float* __restrict__ out) {
    int g = blockIdx.x;
    int c = threadIdx.x;  // 64
    float acc = 0.f;
#pragma unroll
    for (int k = 0; k < 64; ++k) {
        acc = fmaf(P1[g * 64 + k], Wp1[k * 64 + c], acc);
        acc = fmaf(P2[g * 64 + k], Wp2[k * 64 + c], acc);
        acc = fmaf(P3[g * 64 + k], Wp3[k * 64 + c], acc);
    }
    out[g * 64 + c] = fmaxf(acc, 0.f);
}

extern "C" void kernel_launch(void* const* d_in, const int* in_sizes, int n_in,
                              void* d_out, int out_size, void* d_ws, size_t ws_size,
                              hipStream_t stream) {
    const float* x     = (const float*)d_in[0];
    const int*   eidx  = (const int*)d_in[1];   // [2, NE]
    const int*   batch = (const int*)d_in[2];   // [NN], sorted
    const float* W1  = (const float*)d_in[3];
    const float* W2  = (const float*)d_in[4];
    const float* W3  = (const float*)d_in[5];
    const float* Wp1 = (const float*)d_in[6];
    const float* Wp2 = (const float*)d_in[7];
    const float* Wp3 = (const float*)d_in[8];
    float* out = (float*)d_out;

    const int* src = eidx;
    const int* dst = eidx + NE;

    // ---- workspace layout (~35 MB) ----
    float* bufA  = (float*)d_ws;                        // H    (12.8 MB)
    float* bufB  = bufA + (size_t)NN * DIM;             // x_l  (12.8 MB)
    float* pool1 = bufB + (size_t)NN * DIM;             // 3 x 64 KB
    float* pool2 = pool1 + (size_t)NG * DIM;
    float* pool3 = pool2 + (size_t)NG * DIM;
    unsigned int* bucketData = (unsigned int*)(pool3 + (size_t)NG * DIM); // 4.82 MB
    int* gcursor    = (int*)(bucketData + (size_t)NBUCK * BCAP);  // 196
    int* bucketBase = gcursor + NBUCK;                            // 197
    int* offsets    = bucketBase + (NBUCK + 1);                   // NN+1
    int* csr        = offsets + (NN + 1);                         // NE (4 MB)

    hipMemsetAsync(pool1, 0, (size_t)3 * NG * DIM * sizeof(float), stream);
    hipMemsetAsync(gcursor, 0, (size_t)NBUCK * sizeof(int), stream);

    // ---- build exact CSR in 3 launches; reused by all 3 layers ----
    const int fill_blocks = (NE + ROUND - 1) / ROUND;   // 245
    bucket_fill_kernel<<<fill_blocks, 512, 0, stream>>>(src, dst, bucketData, gcursor);
    bucket_base_kernel<<<1, 256, 0, stream>>>(gcursor, bucketBase, offsets);
    bucket_sort_kernel<<<NBUCK, 512, 0, stream>>>(bucketData, gcursor, bucketBase, offsets, csr);

    const int gemm_blocks = (NN + 127) / 128;           // 391
    const int gath_blocks = 2048;                        // 8192 waves

    const float* xin = x;
    const float* Ws[3]   = {W1, W2, W3};
    float* pools[3] = {pool1, pool2, pool3};
    for (int l = 0; l < 3; ++l) {
        gemm64_kernel<<<gemm_blocks, 128, 0, stream>>>(xin, Ws[l], bufA, NN);
        gather_kernel<<<gath_blocks, 256, 0, stream>>>(bufA, offsets, csr, batch, bufB, pools[l]);
        xin = bufB;
    }
    final_kernel<<<NG, 64, 0, stream>>>(pool1, pool2, pool3, Wp1, Wp2, Wp3, out);
}

// Round 7
// 352.197 us; speedup vs baseline: 4.8266x; 1.5534x over previous
//
#include <hip/hip_runtime.h>
#include <hip/hip_bf16.h>

#define NN 50000
#define NE 1000000
#define DIM 64
#define NG 256
#define NBUCK 196        // ceil(NN/256) buckets of 256 dst nodes
#define ROUND 4096       // edges per block in hist2d/permute
#define NBLK 245         // ceil(NE/ROUND)
#define TOT2D (NBUCK * NBLK)   // 48020
#define SCANB 47         // ceil(TOT2D/1024)

// ---- pass 1: per-block bucket histogram -> hist[b*NBLK + blk] ----
__global__ __launch_bounds__(512) void hist2d_kernel(const int* __restrict__ dst,
                                                     int* __restrict__ hist) {
    __shared__ int h[NBUCK];
    int t = threadIdx.x;
    if (t < NBUCK) h[t] = 0;
    __syncthreads();
    int base = blockIdx.x * ROUND;
#pragma unroll
    for (int it = 0; it < 8; ++it) {
        int e = base + it * 512 + t;
        if (e < NE) atomicAdd(&h[dst[e] >> 8], 1);   // LDS atomic, low contention
    }
    __syncthreads();
    if (t < NBUCK) hist[t * NBLK + blockIdx.x] = h[t];
}

// ---- pass 2: flat exclusive scan of hist[TOT2D] (3 tiny kernels) ----
__global__ __launch_bounds__(1024) void scanA_kernel(const int* __restrict__ hist,
                                                     int* __restrict__ blocksum) {
    __shared__ int tmp[1024];
    int t = threadIdx.x;
    int i = blockIdx.x * 1024 + t;
    tmp[t] = (i < TOT2D) ? hist[i] : 0;
    __syncthreads();
    for (int s = 512; s > 0; s >>= 1) {
        if (t < s) tmp[t] += tmp[t + s];
        __syncthreads();
    }
    if (t == 0) blocksum[blockIdx.x] = tmp[0];
}

__global__ __launch_bounds__(64) void scanB_kernel(int* __restrict__ blocksum) {
    __shared__ int tmp[64];
    int t = threadIdx.x;
    int v = (t < SCANB) ? blocksum[t] : 0;
    tmp[t] = v;
    __syncthreads();
    for (int off = 1; off < 64; off <<= 1) {
        int a = (t >= off) ? tmp[t - off] : 0;
        __syncthreads();
        tmp[t] += a;
        __syncthreads();
    }
    if (t < SCANB) blocksum[t] = tmp[t] - v;   // exclusive
}

__global__ __launch_bounds__(1024) void scanC_kernel(const int* __restrict__ hist,
                                                     const int* __restrict__ blocksum,
                                                     int* __restrict__ scanned) {
    __shared__ int tmp[1024];
    int t = threadIdx.x;
    int i = blockIdx.x * 1024 + t;
    int v = (i < TOT2D) ? hist[i] : 0;
    tmp[t] = v;
    __syncthreads();
    for (int off = 1; off < 1024; off <<= 1) {
        int a = (t >= off) ? tmp[t - off] : 0;
        __syncthreads();
        tmp[t] += a;
        __syncthreads();
    }
    if (i < TOT2D) scanned[i] = tmp[t] - v + blocksum[blockIdx.x];
}

// ---- pass 3: permute edges into bucket-major order; positions precomputed,
//      every cache line written by exactly one block (no global atomics) ----
__global__ __launch_bounds__(512) void permute_kernel(
    const int* __restrict__ src, const int* __restrict__ dst,
    const int* __restrict__ scanned, unsigned int* __restrict__ bucketed) {
    __shared__ int cur[NBUCK];
    int t = threadIdx.x;
    int blk = blockIdx.x;
    if (t < NBUCK) cur[t] = scanned[t * NBLK + blk];
    __syncthreads();
    int base = blk * ROUND;
#pragma unroll
    for (int it = 0; it < 8; ++it) {
        int e = base + it * 512 + t;
        if (e < NE) {
            int d = dst[e];
            int s = src[e];
            int b = d >> 8;
            int pos = atomicAdd(&cur[b], 1);     // LDS atomic
            bucketed[pos] = ((unsigned int)(d & 255) << 16) | (unsigned int)s;
        }
    }
}

// ---- pass 4: per-bucket counting sort -> exact CSR (localized writes) ----
__global__ __launch_bounds__(512) void bucket_sort_kernel(
    const unsigned int* __restrict__ bucketed, const int* __restrict__ scanned,
    int* __restrict__ offsets, int* __restrict__ csr) {
    __shared__ int hist[256];
    __shared__ int sc[256];
    __shared__ int cur[256];
    int b = blockIdx.x;
    int t = threadIdx.x;
    if (t < 256) hist[t] = 0;
    __syncthreads();
    int gbase = scanned[b * NBLK];
    int gend  = (b < NBUCK - 1) ? scanned[(b + 1) * NBLK] : NE;
    int count = gend - gbase;
    const unsigned int* bd = bucketed + gbase;
    for (int e = t; e < count; e += 512) atomicAdd(&hist[bd[e] >> 16], 1);
    __syncthreads();
    if (t < 256) sc[t] = hist[t];
    __syncthreads();
    for (int off = 1; off < 256; off <<= 1) {
        int a = 0;
        if (t < 256 && t >= off) a = sc[t - off];
        __syncthreads();
        if (t < 256) sc[t] += a;
        __syncthreads();
    }
    if (t < 256) {
        int excl = sc[t] - hist[t];
        cur[t] = excl;
        int node = b * 256 + t;
        if (node < NN) offsets[node] = gbase + excl;
    }
    if (b == NBUCK - 1 && t == 0) offsets[NN] = NE;
    __syncthreads();
    for (int e = t; e < count; e += 512) {
        unsigned int v = bd[e];
        int p = atomicAdd(&cur[v >> 16], 1);
        csr[gbase + p] = (int)(v & 0xFFFFu);     // writes land in ~20KB range
    }
}

// ---------- H = X @ W : thread-per-row, W via wave-uniform (scalar) loads ----------
__global__ __launch_bounds__(128) void gemm64_kernel(const float* __restrict__ X,
                                                     const float* __restrict__ W,
                                                     float* __restrict__ H, int nrows) {
    __shared__ float Xl[128 * 65];
    int t = threadIdx.x;
    int base = blockIdx.x * 128;
    for (int idx = t; idx < 128 * 16; idx += 128) {
        int row = idx >> 4;
        int c4  = idx & 15;
        float4 v = make_float4(0.f, 0.f, 0.f, 0.f);
        if (base + row < nrows)
            v = *reinterpret_cast<const float4*>(&X[(size_t)(base + row) * 64 + c4 * 4]);
        float* p = &Xl[row * 65 + c4 * 4];
        p[0] = v.x; p[1] = v.y; p[2] = v.z; p[3] = v.w;
    }
    __syncthreads();
    float acc[64];
#pragma unroll
    for (int c = 0; c < 64; ++c) acc[c] = 0.f;
#pragma unroll 4
    for (int k = 0; k < 64; ++k) {
        float xv = Xl[t * 65 + k];
#pragma unroll
        for (int c4 = 0; c4 < 16; ++c4) {
            float4 w = *reinterpret_cast<const float4*>(&W[k * 64 + c4 * 4]);
            acc[c4 * 4 + 0] = fmaf(xv, w.x, acc[c4 * 4 + 0]);
            acc[c4 * 4 + 1] = fmaf(xv, w.y, acc[c4 * 4 + 1]);
            acc[c4 * 4 + 2] = fmaf(xv, w.z, acc[c4 * 4 + 2]);
            acc[c4 * 4 + 3] = fmaf(xv, w.w, acc[c4 * 4 + 3]);
        }
    }
    int row = base + t;
    if (row < nrows) {
#pragma unroll
        for (int c4 = 0; c4 < 16; ++c4) {
            float4 o = make_float4(acc[c4 * 4 + 0], acc[c4 * 4 + 1],
                                   acc[c4 * 4 + 2], acc[c4 * 4 + 3]);
            *reinterpret_cast<float4*>(&H[(size_t)row * 64 + c4 * 4]) = o;
        }
    }
}

// ---------- per-node CSR gather + ReLU + fused add-pool (R3-proven) ----------
__global__ void gather_kernel(const float* __restrict__ H, const int* __restrict__ offsets,
                              const int* __restrict__ csr, const int* __restrict__ batch,
                              float* __restrict__ Xout, float* __restrict__ pool) {
    int tid = blockIdx.x * blockDim.x + threadIdx.x;
    int lane = tid & 63;
    int gw = tid >> 6;
    int nw = (gridDim.x * blockDim.x) >> 6;
    for (int n = gw; n < NN; n += nw) {
        int beg = offsets[n], end = offsets[n + 1];
        float a0 = 0.f, a1 = 0.f, a2 = 0.f, a3 = 0.f;
        int i = beg;
        for (; i + 4 <= end; i += 4) {
            int s0 = csr[i], s1 = csr[i + 1], s2 = csr[i + 2], s3 = csr[i + 3];
            a0 += H[(size_t)s0 * 64 + lane];
            a1 += H[(size_t)s1 * 64 + lane];
            a2 += H[(size_t)s2 * 64 + lane];
            a3 += H[(size_t)s3 * 64 + lane];
        }
        for (; i < end; ++i) a0 += H[(size_t)csr[i] * 64 + lane];
        float v = fmaxf((a0 + a1) + (a2 + a3), 0.f);
        Xout[(size_t)n * 64 + lane] = v;
        unsafeAtomicAdd(&pool[(size_t)batch[n] * 64 + lane], v);
    }
}

// ---------- out[g] = relu(sum_l pool_l[g] @ Wp_l) ----------
__global__ void final_kernel(const float* __restrict__ P1, const float* __restrict__ P2,
                             const float* __restrict__ P3,
                             const float* __restrict__ Wp1, const float* __restrict__ Wp2,
                             const float* __restrict__ Wp3, float* __restrict__ out) {
    int g = blockIdx.x;
    int c = threadIdx.x;  // 64
    float acc = 0.f;
#pragma unroll
    for (int k = 0; k < 64; ++k) {
        acc = fmaf(P1[g * 64 + k], Wp1[k * 64 + c], acc);
        acc = fmaf(P2[g * 64 + k], Wp2[k * 64 + c], acc);
        acc = fmaf(P3[g * 64 + k], Wp3[k * 64 + c], acc);
    }
    out[g * 64 + c] = fmaxf(acc, 0.f);
}

extern "C" void kernel_launch(void* const* d_in, const int* in_sizes, int n_in,
                              void* d_out, int out_size, void* d_ws, size_t ws_size,
                              hipStream_t stream) {
    const float* x     = (const float*)d_in[0];
    const int*   eidx  = (const int*)d_in[1];   // [2, NE]
    const int*   batch = (const int*)d_in[2];   // [NN], sorted
    const float* W1  = (const float*)d_in[3];
    const float* W2  = (const float*)d_in[4];
    const float* W3  = (const float*)d_in[5];
    const float* Wp1 = (const float*)d_in[6];
    const float* Wp2 = (const float*)d_in[7];
    const float* Wp3 = (const float*)d_in[8];
    float* out = (float*)d_out;

    const int* src = eidx;
    const int* dst = eidx + NE;

    // ---- workspace layout (~34.5 MB) ----
    float* bufA  = (float*)d_ws;                        // H    (12.8 MB)
    float* bufB  = bufA + (size_t)NN * DIM;             // x_l  (12.8 MB)
    float* pool1 = bufB + (size_t)NN * DIM;             // 3 x 64 KB
    float* pool2 = pool1 + (size_t)NG * DIM;
    float* pool3 = pool2 + (size_t)NG * DIM;
    int* hist     = (int*)(pool3 + (size_t)NG * DIM);   // TOT2D (192 KB)
    int* scanned  = hist + TOT2D;                       // TOT2D (192 KB)
    int* blocksum = scanned + TOT2D;                    // 64
    int* offsets  = blocksum + 64;                      // NN+1
    unsigned int* bucketed = (unsigned int*)(offsets + NN + 1);  // NE (4 MB)
    int* csr      = (int*)(bucketed + NE);              // NE (4 MB)

    hipMemsetAsync(pool1, 0, (size_t)3 * NG * DIM * sizeof(float), stream);

    // ---- build exact CSR: hist -> scan -> permute -> bucket sort ----
    hist2d_kernel<<<NBLK, 512, 0, stream>>>(dst, hist);
    scanA_kernel<<<SCANB, 1024, 0, stream>>>(hist, blocksum);
    scanB_kernel<<<1, 64, 0, stream>>>(blocksum);
    scanC_kernel<<<SCANB, 1024, 0, stream>>>(hist, blocksum, scanned);
    permute_kernel<<<NBLK, 512, 0, stream>>>(src, dst, scanned, bucketed);
    bucket_sort_kernel<<<NBUCK, 512, 0, stream>>>(bucketed, scanned, offsets, csr);

    const int gemm_blocks = (NN + 127) / 128;           // 391
    const int gath_blocks = 2048;                        // 8192 waves

    const float* xin = x;
    const float* Ws[3]   = {W1, W2, W3};
    float* pools[3] = {pool1, pool2, pool3};
    for (int l = 0; l < 3; ++l) {
        gemm64_kernel<<<gemm_blocks, 128, 0, stream>>>(xin, Ws[l], bufA, NN);
        gather_kernel<<<gath_blocks, 256, 0, stream>>>(bufA, offsets, csr, batch, bufB, pools[l]);
        xin = bufB;
    }
    final_kernel<<<NG, 64, 0, stream>>>(pool1, pool2, pool3, Wp1, Wp2, Wp3, out);
}